// Round 3
// baseline (1812.199 us; speedup 1.0000x reference)
//
#include <hip/hip_runtime.h>
#include <cstdio>
#include <cstdlib>

#define DEVI __device__ __forceinline__

typedef __bf16 bf16_8 __attribute__((ext_vector_type(8)));
typedef float f32x4 __attribute__((ext_vector_type(4)));

DEVI float b2f(unsigned short u){ unsigned int x=((unsigned int)u)<<16; float f; __builtin_memcpy(&f,&x,sizeof(f)); return f; }
DEVI unsigned short f2b(float f){ unsigned int u; __builtin_memcpy(&u,&f,sizeof(u)); u = u + 0x7fffu + ((u>>16)&1u); return (unsigned short)(u>>16); }
DEVI float gelu_f(float x){ return 0.5f*x*(1.0f+erff(x*0.70710678118654752f)); }

DEVI void gload16(const unsigned short* g, unsigned short* l){
  __builtin_amdgcn_global_load_lds((const __attribute__((address_space(1))) void*)g,
                                   (__attribute__((address_space(3))) void*)l, 16, 0, 0);
}

// window-row (win*49+pos) -> pixel index (b*3136 + h*56 + w), folding cyclic
// shift (-3,-3) + window partition (identical mapping forward & reverse).
DEVI int win_row_to_pixel(int row){
  int win = row / 49;
  int pos = row - win*49;
  int b  = win >> 6, wi = win & 63;
  int ph = pos / 7,  pw = pos - ph*7;
  int sh = (wi>>3)*7 + ph, sw = (wi&7)*7 + pw;
  int h = sh + 3; if (h >= 56) h -= 56;
  int w = sw + 3; if (w >= 56) w -= 56;
  return b*3136 + h*56 + w;
}

// ---------------- GEMM: C[M,N] = A[M,K] @ Bw[N,K]^T  (bf16 in, fp32 acc) ----
// A row index = am0 + local (EPI0: then remapped via win_row_to_pixel).
// EPI 0: out bf16 [CH,768] local rows (+qkv_b)
// EPI 1: out fp32 at win_row_to_pixel(om0+local): acc + proj_b + x + 0.1*xl
// EPI 2: out bf16 gelu(acc + bias), local rows, row stride = gridDim.x*128
// EPI 3: out fp32 at global row om0+local: acc + bias + aux0  (final residual)
template<int K, int EPI>
__global__ __launch_bounds__(256)
void gemm_k(const unsigned short* __restrict__ A, const unsigned short* __restrict__ Bw,
            const float* __restrict__ bias, void* __restrict__ outp,
            const float* __restrict__ aux0, const unsigned short* __restrict__ aux1,
            int am0, int om0)
{
  __shared__ unsigned short As[2][128*64];
  __shared__ unsigned short Bs[2][128*64];
  const int tid = threadIdx.x;
  const int wave = tid >> 6, lane = tid & 63;
  const int tn = blockIdx.x, tm = blockIdx.y;
  const int g = lane >> 4, c = lane & 15;

  const unsigned short* ap[4];
  const unsigned short* bp[4];
  {
    int coff = (lane & 7) * 8;
    int rb = wave*32 + (lane >> 3);
#pragma unroll
    for (int j = 0; j < 4; j++){
      int r = rb + j*8;
      int am = am0 + tm*128 + r;
      int arow = (EPI == 0) ? win_row_to_pixel(am) : am;
      ap[j] = A  + (size_t)arow * K + coff;
      bp[j] = Bw + (size_t)(tn*128 + r) * K + coff;
    }
  }
  const f32x4 z4 = {0.f,0.f,0.f,0.f};
  f32x4 acc[4][4];
#pragma unroll
  for (int mi=0;mi<4;mi++)
#pragma unroll
    for (int ni=0;ni<4;ni++) acc[mi][ni] = z4;

  const int wr = wave >> 1, wc = wave & 1;
  const int ldsoff = wave*2048;

  // prologue: stage K-step 0 into buf 0
#pragma unroll
  for (int j=0;j<4;j++){
    gload16(ap[j], &As[0][ldsoff + j*512]);
    gload16(bp[j], &Bs[0][ldsoff + j*512]);
  }
  __syncthreads();   // compiler emits vmcnt(0) drain here

  constexpr int NK = K/64;
  int cur = 0;
  for (int ks=0; ks<NK; ks++){
    if (ks+1 < NK){
      int k0 = (ks+1)*64;
#pragma unroll
      for (int j=0;j<4;j++){
        gload16(ap[j]+k0, &As[cur^1][ldsoff + j*512]);
        gload16(bp[j]+k0, &Bs[cur^1][ldsoff + j*512]);
      }
    }
#pragma unroll
    for (int kk=0;kk<2;kk++){
      bf16_8 af[4], bfr[4];
#pragma unroll
      for (int mi=0;mi<4;mi++) af[mi]  = *(const bf16_8*)&As[cur][(wr*64+mi*16+c)*64 + kk*32 + g*8];
#pragma unroll
      for (int ni=0;ni<4;ni++) bfr[ni] = *(const bf16_8*)&Bs[cur][(wc*64+ni*16+c)*64 + kk*32 + g*8];
#pragma unroll
      for (int mi=0;mi<4;mi++)
#pragma unroll
        for (int ni=0;ni<4;ni++)
          acc[mi][ni] = __builtin_amdgcn_mfma_f32_16x16x32_bf16(af[mi], bfr[ni], acc[mi][ni], 0,0,0);
    }
    __syncthreads();   // drains prefetch vmcnt + all ds reads
    cur ^= 1;
  }

  const int N = gridDim.x * 128;
#pragma unroll
  for (int mi=0;mi<4;mi++){
#pragma unroll
    for (int r=0;r<4;r++){
      int lrow = tm*128 + wr*64 + mi*16 + g*4 + r;
      int pix = 0;
      if constexpr (EPI == 1) pix = win_row_to_pixel(om0 + lrow);
#pragma unroll
      for (int ni=0;ni<4;ni++){
        int col = tn*128 + wc*64 + ni*16 + c;
        float v = acc[mi][ni][r] + bias[col];
        if constexpr (EPI == 0){
          ((unsigned short*)outp)[(size_t)lrow*768 + col] = f2b(v);
        } else if constexpr (EPI == 1){
          size_t idx = (size_t)pix*256 + col;
          ((float*)outp)[idx] = v + aux0[idx] + 0.1f*b2f(aux1[idx]);
        } else if constexpr (EPI == 2){
          ((unsigned short*)outp)[(size_t)lrow*N + col] = f2b(gelu_f(v));
        } else {
          size_t idx = (size_t)(om0 + lrow)*256 + col;
          ((float*)outp)[idx] = v + aux0[idx];
        }
      }
    }
  }
}

// ---------------- Attention (diagnostic-simple): 1 wave per (window, head) --
// fp32 vector-ALU, direct transcription of the reference math. K/V staged in
// LDS as uint-packed bf16 pairs; per-thread (= per query row) full softmax.
__global__ __launch_bounds__(512)
void attn_kernel(const unsigned short* __restrict__ qkv, const float* __restrict__ rpb,
                 unsigned short* __restrict__ out, int win_base)
{
  __shared__ unsigned int KV[8][49*16*2];   // per head: K rows then V rows
  const int lwin = blockIdx.x;
  const int head = threadIdx.x >> 6, lane = threadIdx.x & 63;
  const int wi = (win_base + lwin) & 63, wh = wi >> 3, ww = wi & 7;
  const unsigned short* base = qkv + (size_t)lwin*49*768 + head*32;

  for (int i = lane; i < 49*16; i += 64){
    int m = i >> 4, d2 = i & 15;
    KV[head][i]       = *(const unsigned int*)(base + 256 + (size_t)m*768 + d2*2);
    KV[head][784 + i] = *(const unsigned int*)(base + 512 + (size_t)m*768 + d2*2);
  }
  __syncthreads();
  const int n = lane;
  if (n >= 49) return;

  float q[32];
#pragma unroll
  for (int d2 = 0; d2 < 16; d2++){
    unsigned int u = *(const unsigned int*)(base + (size_t)n*768 + d2*2);
    q[d2*2]   = b2f((unsigned short)(u & 0xffffu));
    q[d2*2+1] = b2f((unsigned short)(u >> 16));
  }
  const int yn = n/7, xq = n - (n/7)*7;
  const int syn = wh*7+yn, sxn = ww*7+xq;
  const int regn = ((syn<49)?0:((syn<53)?1:2))*3 + ((sxn<49)?0:((sxn<53)?1:2));
  const float scale = 0.17677669529663687f;  // 1/sqrt(32)

  float p[49]; float mx = -1e30f;
#pragma unroll
  for (int m = 0; m < 49; m++){
    float s = 0.f;
#pragma unroll
    for (int d2 = 0; d2 < 16; d2++){
      unsigned int u = KV[head][m*16 + d2];
      s += q[d2*2]   * b2f((unsigned short)(u & 0xffffu));
      s += q[d2*2+1] * b2f((unsigned short)(u >> 16));
    }
    int ym = m/7, xm = m - (m/7)*7;
    int sym = wh*7+ym, sxm = ww*7+xm;
    int regm = ((sym<49)?0:((sym<53)?1:2))*3 + ((sxm<49)?0:((sxm<53)?1:2));
    float v = s*scale + rpb[((yn-ym+6)*13 + (xq-xm+6))*8 + head]
            + ((regn!=regm) ? -100.f : 0.f);
    p[m] = v; mx = fmaxf(mx, v);
  }
  float sum = 0.f;
#pragma unroll
  for (int m = 0; m < 49; m++){ p[m] = __expf(p[m]-mx); sum += p[m]; }
  const float inv = 1.0f/sum;

  float o[32];
#pragma unroll
  for (int d = 0; d < 32; d++) o[d] = 0.f;
#pragma unroll
  for (int m = 0; m < 49; m++){
    float pm = p[m]*inv;
#pragma unroll
    for (int d2 = 0; d2 < 16; d2++){
      unsigned int u = KV[head][784 + m*16 + d2];
      o[d2*2]   += pm * b2f((unsigned short)(u & 0xffffu));
      o[d2*2+1] += pm * b2f((unsigned short)(u >> 16));
    }
  }
  size_t ob = ((size_t)lwin*49 + n)*256 + head*32;
#pragma unroll
  for (int d2 = 0; d2 < 16; d2++){
    unsigned int w = (unsigned int)f2b(o[d2*2]) | ((unsigned int)f2b(o[d2*2+1])<<16);
    *(unsigned int*)&out[ob + d2*2] = w;
  }
}

// ---------------- LayerNorm over C=256, fp32 in -> bf16 out -----------------
__global__ __launch_bounds__(256)
void ln_kernel(const float* __restrict__ x, const float* __restrict__ gw,
               const float* __restrict__ bw, unsigned short* __restrict__ out)
{
  const int wave = threadIdx.x >> 6, lane = threadIdx.x & 63;
  const size_t row = (size_t)blockIdx.x*4 + wave;
  const float4 v = *(const float4*)&x[row*256 + lane*4];
  float s = v.x+v.y+v.z+v.w;
  float q = v.x*v.x+v.y*v.y+v.z*v.z+v.w*v.w;
#pragma unroll
  for (int m=1;m<64;m<<=1){ s += __shfl_xor(s,m); q += __shfl_xor(q,m); }
  float mean = s*(1.0f/256.0f);
  float var  = q*(1.0f/256.0f) - mean*mean;
  float rstd = rsqrtf(var + 1e-5f);
  const float4 gg = *(const float4*)&gw[lane*4];
  const float4 bb = *(const float4*)&bw[lane*4];
  unsigned int lo = (unsigned int)f2b((v.x-mean)*rstd*gg.x + bb.x)
                  | ((unsigned int)f2b((v.y-mean)*rstd*gg.y + bb.y) << 16);
  unsigned int hi = (unsigned int)f2b((v.z-mean)*rstd*gg.z + bb.z)
                  | ((unsigned int)f2b((v.w-mean)*rstd*gg.w + bb.w) << 16);
  *(uint2*)&out[row*256 + lane*4] = make_uint2(lo, hi);
}

// ---------------- depthwise 3x3 'SAME' conv, bf16 in/out --------------------
__global__ __launch_bounds__(256)
void dwconv_kernel(const unsigned short* __restrict__ xn, const float* __restrict__ w,
                   const float* __restrict__ bias, unsigned short* __restrict__ out)
{
  int idx = blockIdx.x*256 + threadIdx.x;      // [0, 32*3136*64)
  int c4  = idx & 63;
  int t   = idx >> 6;                          // b*3136 + pix
  int b   = t / 3136;
  int pix = t - b*3136;
  int h = pix / 56, wq = pix - h*56;
  float4 acc = *(const float4*)&bias[c4*4];
#pragma unroll
  for (int ky=0;ky<3;ky++){
    int hy = h + ky - 1;
    if ((unsigned)hy >= 56u) continue;
#pragma unroll
    for (int kx=0;kx<3;kx++){
      int wx = wq + kx - 1;
      if ((unsigned)wx >= 56u) continue;
      const uint2 raw = *(const uint2*)&xn[(((size_t)b*3136 + hy*56 + wx)<<8) + c4*4];
      const float4 wv = *(const float4*)&w[((ky*3+kx)<<8) + c4*4];
      acc.x += b2f((unsigned short)(raw.x & 0xffffu)) * wv.x;
      acc.y += b2f((unsigned short)(raw.x >> 16))     * wv.y;
      acc.z += b2f((unsigned short)(raw.y & 0xffffu)) * wv.z;
      acc.w += b2f((unsigned short)(raw.y >> 16))     * wv.w;
    }
  }
  unsigned int lo = (unsigned int)f2b(acc.x) | ((unsigned int)f2b(acc.y)<<16);
  unsigned int hi = (unsigned int)f2b(acc.z) | ((unsigned int)f2b(acc.w)<<16);
  *(uint2*)&out[(size_t)idx*4] = make_uint2(lo,hi);
}

// ---------------- fp32 -> bf16 weight convert (float4 per thread) -----------
__global__ void cvt_kernel(const float* __restrict__ in, unsigned short* __restrict__ out, int n4)
{
  int i = blockIdx.x*256 + threadIdx.x;
  if (i < n4){
    float4 v = ((const float4*)in)[i];
    unsigned int lo = (unsigned int)f2b(v.x) | ((unsigned int)f2b(v.y)<<16);
    unsigned int hi = (unsigned int)f2b(v.z) | ((unsigned int)f2b(v.w)<<16);
    ((uint2*)out)[i] = make_uint2(lo,hi);
  }
}

extern "C" void kernel_launch(void* const* d_in, const int* in_sizes, int n_in,
                              void* d_out, int out_size, void* d_ws, size_t ws_size,
                              hipStream_t stream)
{
  (void)in_sizes; (void)n_in; (void)out_size;
  const float* x     = (const float*)d_in[0];
  const float* ln1g  = (const float*)d_in[1];
  const float* ln1b  = (const float*)d_in[2];
  const float* dww   = (const float*)d_in[3];
  const float* dwb   = (const float*)d_in[4];
  const float* qkvw  = (const float*)d_in[5];
  const float* qkvb  = (const float*)d_in[6];
  const float* rpb   = (const float*)d_in[7];
  const float* projw = (const float*)d_in[8];
  const float* projb = (const float*)d_in[9];
  const float* ln2g  = (const float*)d_in[10];
  const float* ln2b  = (const float*)d_in[11];
  const float* w1    = (const float*)d_in[12];
  const float* b1    = (const float*)d_in[13];
  const float* w2    = (const float*)d_in[14];
  const float* b2    = (const float*)d_in[15];
  const float* w3    = (const float*)d_in[16];
  const float* b3    = (const float*)d_in[17];

  // ---- adaptive workspace layout (x2 residual lives in d_out, fp32) ----
  char* ws = (char*)d_ws;
  constexpr size_t OFF_XN = 3670016;                 // bf16 weights precede
  constexpr size_t OFF_XL = OFF_XN + 51380224;
  constexpr size_t OFF_S  = OFF_XL + 51380224;       // 106,430,464
  int CH = 6272;                                     // rows/chunk, mult of lcm(128,49)
  if      (ws_size >= OFF_S + 100352ull*4096) CH = 100352;
  else if (ws_size >= OFF_S + 50176ull*4096)  CH = 50176;
  else if (ws_size >= OFF_S + 25088ull*2048)  CH = 25088;
  else if (ws_size >= OFF_S + 12544ull*2048)  CH = 12544;
  const int NC = 100352 / CH;

  unsigned short* wqkv = (unsigned short*)(ws + 0);
  unsigned short* wproj= wqkv + 196608;
  unsigned short* wm1  = wproj + 65536;
  unsigned short* wm2  = wm1 + 262144;
  unsigned short* wm3  = wm2 + 1048576;
  unsigned short* xn   = (unsigned short*)(ws + OFF_XN);
  unsigned short* xl   = (unsigned short*)(ws + OFF_XL);
  unsigned short* qkvc = (unsigned short*)(ws + OFF_S);
  unsigned short* aoc  = (unsigned short*)(ws + OFF_S + (size_t)CH*1536);
  unsigned short* h2c  = (unsigned short*)(ws + OFF_S);
  unsigned short* h1c  = (CH <= 25088) ? (unsigned short*)(ws + OFF_XL)
                                       : (unsigned short*)(ws + OFF_S + (size_t)CH*2048);
  float* x2 = (float*)d_out;

  cvt_kernel<<<192,  256, 0, stream>>>(qkvw,  wqkv,  49152);
  cvt_kernel<<<64,   256, 0, stream>>>(projw, wproj, 16384);
  cvt_kernel<<<256,  256, 0, stream>>>(w1,    wm1,   65536);
  cvt_kernel<<<1024, 256, 0, stream>>>(w2,    wm2,   262144);
  cvt_kernel<<<256,  256, 0, stream>>>(w3,    wm3,   65536);

  ln_kernel<<<25088, 256, 0, stream>>>(x, ln1g, ln1b, xn);
  dwconv_kernel<<<25088, 256, 0, stream>>>(xn, dww, dwb, xl);

  for (int cch = 0; cch < NC; ++cch){
    int m0 = cch * CH;
    gemm_k<256,0><<<dim3(6, CH/128), 256, 0, stream>>>(xn, wqkv, qkvb, qkvc, nullptr, nullptr, m0, 0);
    attn_kernel<<<CH/49, 512, 0, stream>>>(qkvc, rpb, aoc, m0/49);
    gemm_k<256,1><<<dim3(2, CH/128), 256, 0, stream>>>(aoc, wproj, projb, x2, x, xl, 0, m0);
  }

  ln_kernel<<<25088, 256, 0, stream>>>(x2, ln2g, ln2b, xn);   // xn reused as LN2 out

  for (int cch = 0; cch < NC; ++cch){
    int m0 = cch * CH;
    gemm_k<256,2> <<<dim3(8, CH/128), 256, 0, stream>>>(xn,  wm1, b1, h1c, nullptr, nullptr, m0, 0);
    gemm_k<1024,2><<<dim3(8, CH/128), 256, 0, stream>>>(h1c, wm2, b2, h2c, nullptr, nullptr, 0, 0);
    gemm_k<1024,3><<<dim3(2, CH/128), 256, 0, stream>>>(h2c, wm3, b3, x2, x2, nullptr, 0, m0);
  }
}

// Round 5
// 1774.523 us; speedup vs baseline: 1.0212x; 1.0212x over previous
//
#include <hip/hip_runtime.h>
#include <cstdio>
#include <cstdlib>

#define DEVI __device__ __forceinline__

typedef __bf16 bf16_8 __attribute__((ext_vector_type(8)));
typedef float f32x4 __attribute__((ext_vector_type(4)));

DEVI float b2f(unsigned short u){ unsigned int x=((unsigned int)u)<<16; float f; __builtin_memcpy(&f,&x,sizeof(f)); return f; }
DEVI unsigned short f2b(float f){ unsigned int u; __builtin_memcpy(&u,&f,sizeof(u)); u = u + 0x7fffu + ((u>>16)&1u); return (unsigned short)(u>>16); }
DEVI float gelu_f(float x){ return 0.5f*x*(1.0f+erff(x*0.70710678118654752f)); }

DEVI void gload16(const unsigned short* g, unsigned short* l){
  __builtin_amdgcn_global_load_lds((const __attribute__((address_space(1))) void*)g,
                                   (__attribute__((address_space(3))) void*)l, 16, 0, 0);
}

// window-row (win*49+pos) -> pixel index (b*3136 + h*56 + w), folding cyclic
// shift (-3,-3) + window partition (identical mapping forward & reverse).
DEVI int win_row_to_pixel(int row){
  int win = row / 49;
  int pos = row - win*49;
  int b  = win >> 6, wi = win & 63;
  int ph = pos / 7,  pw = pos - ph*7;
  int sh = (wi>>3)*7 + ph, sw = (wi&7)*7 + pw;
  int h = sh + 3; if (h >= 56) h -= 56;
  int w = sw + 3; if (w >= 56) w -= 56;
  return b*3136 + h*56 + w;
}

// ---------------- GEMM: C[M,N] = A[M,K] @ Bw[N,K]^T  (bf16 in, fp32 acc) ----
// T1: bijective chunked XCD swizzle (all grids have nwg%8==0): XCD c covers a
// contiguous tm-range x all tn -> A-tile L2 reuse across N-tiles in one XCD.
// EPI 0: A-rows remapped via win_row_to_pixel(am0+r); out bf16 [CH,768] (+qkv_b)
// EPI 1: out fp32 at win_row_to_pixel(om0+local): acc + proj_b + x + 0.1*xl
// EPI 2: out bf16 gelu(acc + bias), local rows, row stride NX*128
// EPI 3: out fp32 at global row om0+local: acc + bias + aux0  (final residual)
template<int K, int EPI, int NX>
__global__ __launch_bounds__(256)
void gemm_k(const unsigned short* __restrict__ A, const unsigned short* __restrict__ Bw,
            const float* __restrict__ bias, void* __restrict__ outp,
            const float* __restrict__ aux0, const unsigned short* __restrict__ aux1,
            int am0, int om0)
{
  __shared__ unsigned short As[2][128*64];
  __shared__ unsigned short Bs[2][128*64];
  const int tid = threadIdx.x;
  const int wave = tid >> 6, lane = tid & 63;
  // T1 chunked swizzle: hardware id L runs on XCD L%8; give XCD c the
  // contiguous logical range [c*chunk, (c+1)*chunk).
  const int L = blockIdx.y * NX + blockIdx.x;
  const int chunk = (NX * gridDim.y) >> 3;
  const int swz = (L & 7) * chunk + (L >> 3);
  const int tm = swz / NX, tn = swz - tm * NX;
  const int g = lane >> 4, c = lane & 15;

  const unsigned short* ap[4];
  const unsigned short* bp[4];
  {
    int coff = (lane & 7) * 8;
    int rb = wave*32 + (lane >> 3);
#pragma unroll
    for (int j = 0; j < 4; j++){
      int r = rb + j*8;
      int am = am0 + tm*128 + r;
      int arow = (EPI == 0) ? win_row_to_pixel(am) : am;
      ap[j] = A  + (size_t)arow * K + coff;
      bp[j] = Bw + (size_t)(tn*128 + r) * K + coff;
    }
  }
  const f32x4 z4 = {0.f,0.f,0.f,0.f};
  f32x4 acc[4][4];
#pragma unroll
  for (int mi=0;mi<4;mi++)
#pragma unroll
    for (int ni=0;ni<4;ni++) acc[mi][ni] = z4;

  const int wr = wave >> 1, wc = wave & 1;
  const int ldsoff = wave*2048;

  // prologue: stage K-step 0 into buf 0
#pragma unroll
  for (int j=0;j<4;j++){
    gload16(ap[j], &As[0][ldsoff + j*512]);
    gload16(bp[j], &Bs[0][ldsoff + j*512]);
  }
  __syncthreads();   // compiler emits vmcnt(0) drain here

  constexpr int NK = K/64;
  int cur = 0;
  for (int ks=0; ks<NK; ks++){
    if (ks+1 < NK){
      int k0 = (ks+1)*64;
#pragma unroll
      for (int j=0;j<4;j++){
        gload16(ap[j]+k0, &As[cur^1][ldsoff + j*512]);
        gload16(bp[j]+k0, &Bs[cur^1][ldsoff + j*512]);
      }
    }
#pragma unroll
    for (int kk=0;kk<2;kk++){
      bf16_8 af[4], bfr[4];
#pragma unroll
      for (int mi=0;mi<4;mi++) af[mi]  = *(const bf16_8*)&As[cur][(wr*64+mi*16+c)*64 + kk*32 + g*8];
#pragma unroll
      for (int ni=0;ni<4;ni++) bfr[ni] = *(const bf16_8*)&Bs[cur][(wc*64+ni*16+c)*64 + kk*32 + g*8];
#pragma unroll
      for (int mi=0;mi<4;mi++)
#pragma unroll
        for (int ni=0;ni<4;ni++)
          acc[mi][ni] = __builtin_amdgcn_mfma_f32_16x16x32_bf16(af[mi], bfr[ni], acc[mi][ni], 0,0,0);
    }
    __syncthreads();   // drains prefetch vmcnt + all ds reads
    cur ^= 1;
  }

#pragma unroll
  for (int mi=0;mi<4;mi++){
#pragma unroll
    for (int r=0;r<4;r++){
      int lrow = tm*128 + wr*64 + mi*16 + g*4 + r;
      int pix = 0;
      if constexpr (EPI == 1) pix = win_row_to_pixel(om0 + lrow);
#pragma unroll
      for (int ni=0;ni<4;ni++){
        int col = tn*128 + wc*64 + ni*16 + c;
        float v = acc[mi][ni][r] + bias[col];
        if constexpr (EPI == 0){
          ((unsigned short*)outp)[(size_t)lrow*768 + col] = f2b(v);
        } else if constexpr (EPI == 1){
          size_t idx = (size_t)pix*256 + col;
          ((float*)outp)[idx] = v + aux0[idx] + 0.1f*b2f(aux1[idx]);
        } else if constexpr (EPI == 2){
          ((unsigned short*)outp)[(size_t)lrow*(NX*128) + col] = f2b(gelu_f(v));
        } else {
          size_t idx = (size_t)(om0 + lrow)*256 + col;
          ((float*)outp)[idx] = v + aux0[idx];
        }
      }
    }
  }
}

// ---------------- Attention: 1 wave per (window, head), spill-free ----------
// Per-thread query row; two-pass online softmax (no p[49] array -> no scratch).
// Math lines are verbatim from the round-3 verified version.
__global__ __launch_bounds__(512)
void attn_kernel(const unsigned short* __restrict__ qkv, const float* __restrict__ rpb,
                 unsigned short* __restrict__ out, int win_base)
{
  __shared__ unsigned int KV[8][49*16*2];   // per head: K rows then V rows
  const int lwin = blockIdx.x;
  const int head = threadIdx.x >> 6, lane = threadIdx.x & 63;
  const int wi = (win_base + lwin) & 63, wh = wi >> 3, ww = wi & 7;
  const unsigned short* base = qkv + (size_t)lwin*49*768 + head*32;

  for (int i = lane; i < 49*16; i += 64){
    int m = i >> 4, d2 = i & 15;
    KV[head][i]       = *(const unsigned int*)(base + 256 + (size_t)m*768 + d2*2);
    KV[head][784 + i] = *(const unsigned int*)(base + 512 + (size_t)m*768 + d2*2);
  }
  __syncthreads();
  const int n = lane;
  if (n >= 49) return;

  float q[32];
#pragma unroll
  for (int d2 = 0; d2 < 16; d2++){
    unsigned int u = *(const unsigned int*)(base + (size_t)n*768 + d2*2);
    q[d2*2]   = b2f((unsigned short)(u & 0xffffu));
    q[d2*2+1] = b2f((unsigned short)(u >> 16));
  }
  const int yn = n/7, xq = n - (n/7)*7;
  const int syn = wh*7+yn, sxn = ww*7+xq;
  const int regn = ((syn<49)?0:((syn<53)?1:2))*3 + ((sxn<49)?0:((sxn<53)?1:2));
  const float scale = 0.17677669529663687f;  // 1/sqrt(32)

  // pass 1: online max + sum (scalar rescale only)
  float mx = -1e30f, sum = 0.f;
  for (int m = 0; m < 49; m++){
    float s = 0.f;
#pragma unroll
    for (int d2 = 0; d2 < 16; d2++){
      unsigned int u = KV[head][m*16 + d2];
      s += q[d2*2]   * b2f((unsigned short)(u & 0xffffu));
      s += q[d2*2+1] * b2f((unsigned short)(u >> 16));
    }
    int ym = m/7, xm = m - (m/7)*7;
    int sym = wh*7+ym, sxm = ww*7+xm;
    int regm = ((sym<49)?0:((sym<53)?1:2))*3 + ((sxm<49)?0:((sxm<53)?1:2));
    float v = s*scale + rpb[((yn-ym+6)*13 + (xq-xm+6))*8 + head]
            + ((regn!=regm) ? -100.f : 0.f);
    float nm = fmaxf(mx, v);
    sum = sum*__expf(mx - nm) + __expf(v - nm);
    mx = nm;
  }
  const float inv = 1.0f/sum;

  // pass 2: recompute scores, accumulate o (unnormalized), scale at the end
  float o[32];
#pragma unroll
  for (int d = 0; d < 32; d++) o[d] = 0.f;
  for (int m = 0; m < 49; m++){
    float s = 0.f;
#pragma unroll
    for (int d2 = 0; d2 < 16; d2++){
      unsigned int u = KV[head][m*16 + d2];
      s += q[d2*2]   * b2f((unsigned short)(u & 0xffffu));
      s += q[d2*2+1] * b2f((unsigned short)(u >> 16));
    }
    int ym = m/7, xm = m - (m/7)*7;
    int sym = wh*7+ym, sxm = ww*7+xm;
    int regm = ((sym<49)?0:((sym<53)?1:2))*3 + ((sxm<49)?0:((sxm<53)?1:2));
    float v = s*scale + rpb[((yn-ym+6)*13 + (xq-xm+6))*8 + head]
            + ((regn!=regm) ? -100.f : 0.f);
    float pm = __expf(v - mx);
#pragma unroll
    for (int d2 = 0; d2 < 16; d2++){
      unsigned int u = KV[head][784 + m*16 + d2];
      o[d2*2]   += pm * b2f((unsigned short)(u & 0xffffu));
      o[d2*2+1] += pm * b2f((unsigned short)(u >> 16));
    }
  }
  size_t ob = ((size_t)lwin*49 + n)*256 + head*32;
#pragma unroll
  for (int d2 = 0; d2 < 16; d2++){
    unsigned int w = (unsigned int)f2b(o[d2*2]*inv) | ((unsigned int)f2b(o[d2*2+1]*inv)<<16);
    *(unsigned int*)&out[ob + d2*2] = w;
  }
}

// ---------------- LayerNorm over C=256, fp32 in -> bf16 out -----------------
__global__ __launch_bounds__(256)
void ln_kernel(const float* __restrict__ x, const float* __restrict__ gw,
               const float* __restrict__ bw, unsigned short* __restrict__ out)
{
  const int wave = threadIdx.x >> 6, lane = threadIdx.x & 63;
  const size_t row = (size_t)blockIdx.x*4 + wave;
  const float4 v = *(const float4*)&x[row*256 + lane*4];
  float s = v.x+v.y+v.z+v.w;
  float q = v.x*v.x+v.y*v.y+v.z*v.z+v.w*v.w;
#pragma unroll
  for (int m=1;m<64;m<<=1){ s += __shfl_xor(s,m); q += __shfl_xor(q,m); }
  float mean = s*(1.0f/256.0f);
  float var  = q*(1.0f/256.0f) - mean*mean;
  float rstd = rsqrtf(var + 1e-5f);
  const float4 gg = *(const float4*)&gw[lane*4];
  const float4 bb = *(const float4*)&bw[lane*4];
  unsigned int lo = (unsigned int)f2b((v.x-mean)*rstd*gg.x + bb.x)
                  | ((unsigned int)f2b((v.y-mean)*rstd*gg.y + bb.y) << 16);
  unsigned int hi = (unsigned int)f2b((v.z-mean)*rstd*gg.z + bb.z)
                  | ((unsigned int)f2b((v.w-mean)*rstd*gg.w + bb.w) << 16);
  *(uint2*)&out[row*256 + lane*4] = make_uint2(lo, hi);
}

// ---------------- depthwise 3x3 'SAME' conv, bf16 in/out --------------------
__global__ __launch_bounds__(256)
void dwconv_kernel(const unsigned short* __restrict__ xn, const float* __restrict__ w,
                   const float* __restrict__ bias, unsigned short* __restrict__ out)
{
  int idx = blockIdx.x*256 + threadIdx.x;      // [0, 32*3136*64)
  int c4  = idx & 63;
  int t   = idx >> 6;                          // b*3136 + pix
  int b   = t / 3136;
  int pix = t - b*3136;
  int h = pix / 56, wq = pix - h*56;
  float4 acc = *(const float4*)&bias[c4*4];
#pragma unroll
  for (int ky=0;ky<3;ky++){
    int hy = h + ky - 1;
    if ((unsigned)hy >= 56u) continue;
#pragma unroll
    for (int kx=0;kx<3;kx++){
      int wx = wq + kx - 1;
      if ((unsigned)wx >= 56u) continue;
      const uint2 raw = *(const uint2*)&xn[(((size_t)b*3136 + hy*56 + wx)<<8) + c4*4];
      const float4 wv = *(const float4*)&w[((ky*3+kx)<<8) + c4*4];
      acc.x += b2f((unsigned short)(raw.x & 0xffffu)) * wv.x;
      acc.y += b2f((unsigned short)(raw.x >> 16))     * wv.y;
      acc.z += b2f((unsigned short)(raw.y & 0xffffu)) * wv.z;
      acc.w += b2f((unsigned short)(raw.y >> 16))     * wv.w;
    }
  }
  unsigned int lo = (unsigned int)f2b(acc.x) | ((unsigned int)f2b(acc.y)<<16);
  unsigned int hi = (unsigned int)f2b(acc.z) | ((unsigned int)f2b(acc.w)<<16);
  *(uint2*)&out[(size_t)idx*4] = make_uint2(lo,hi);
}

// ---------------- fp32 -> bf16 weight convert (float4 per thread) -----------
__global__ void cvt_kernel(const float* __restrict__ in, unsigned short* __restrict__ out, int n4)
{
  int i = blockIdx.x*256 + threadIdx.x;
  if (i < n4){
    float4 v = ((const float4*)in)[i];
    unsigned int lo = (unsigned int)f2b(v.x) | ((unsigned int)f2b(v.y)<<16);
    unsigned int hi = (unsigned int)f2b(v.z) | ((unsigned int)f2b(v.w)<<16);
    ((uint2*)out)[i] = make_uint2(lo,hi);
  }
}

extern "C" void kernel_launch(void* const* d_in, const int* in_sizes, int n_in,
                              void* d_out, int out_size, void* d_ws, size_t ws_size,
                              hipStream_t stream)
{
  (void)in_sizes; (void)n_in; (void)out_size; (void)ws_size;
  const float* x     = (const float*)d_in[0];
  const float* ln1g  = (const float*)d_in[1];
  const float* ln1b  = (const float*)d_in[2];
  const float* dww   = (const float*)d_in[3];
  const float* dwb   = (const float*)d_in[4];
  const float* qkvw  = (const float*)d_in[5];
  const float* qkvb  = (const float*)d_in[6];
  const float* rpb   = (const float*)d_in[7];
  const float* projw = (const float*)d_in[8];
  const float* projb = (const float*)d_in[9];
  const float* ln2g  = (const float*)d_in[10];
  const float* ln2b  = (const float*)d_in[11];
  const float* w1    = (const float*)d_in[12];
  const float* b1    = (const float*)d_in[13];
  const float* w2    = (const float*)d_in[14];
  const float* b2    = (const float*)d_in[15];
  const float* w3    = (const float*)d_in[16];
  const float* b3    = (const float*)d_in[17];

  // ---- workspace layout (x2 residual lives in d_out, fp32) ----
  // CH=25088 chunks keep qkvc/aoc and h1c/h2c LLC-resident (<=77MB live).
  // r3 ran the full-M tier => ws_size >= 517MB, far above the 209MB used here.
  char* ws = (char*)d_ws;
  constexpr size_t OFF_XN = 3670016;                 // bf16 weights precede
  constexpr size_t OFF_XL = OFF_XN + 51380224;
  constexpr size_t OFF_S  = OFF_XL + 51380224;       // 106,430,464
  constexpr int CH = 25088;                          // mult of 128 and 49*512
  constexpr int NC = 100352 / CH;

  unsigned short* wqkv = (unsigned short*)(ws + 0);
  unsigned short* wproj= wqkv + 196608;
  unsigned short* wm1  = wproj + 65536;
  unsigned short* wm2  = wm1 + 262144;
  unsigned short* wm3  = wm2 + 1048576;
  unsigned short* xn   = (unsigned short*)(ws + OFF_XN);
  unsigned short* xl   = (unsigned short*)(ws + OFF_XL);
  unsigned short* qkvc = (unsigned short*)(ws + OFF_S);
  unsigned short* aoc  = (unsigned short*)(ws + OFF_S + (size_t)CH*1536);
  unsigned short* h2c  = (unsigned short*)(ws + OFF_S);       // reuses qkvc/aoc
  unsigned short* h1c  = (unsigned short*)(ws + OFF_XL);      // reuses xl (dead)
  float* x2 = (float*)d_out;

  cvt_kernel<<<192,  256, 0, stream>>>(qkvw,  wqkv,  49152);
  cvt_kernel<<<64,   256, 0, stream>>>(projw, wproj, 16384);
  cvt_kernel<<<256,  256, 0, stream>>>(w1,    wm1,   65536);
  cvt_kernel<<<1024, 256, 0, stream>>>(w2,    wm2,   262144);
  cvt_kernel<<<256,  256, 0, stream>>>(w3,    wm3,   65536);

  ln_kernel<<<25088, 256, 0, stream>>>(x, ln1g, ln1b, xn);
  dwconv_kernel<<<25088, 256, 0, stream>>>(xn, dww, dwb, xl);

  for (int cch = 0; cch < NC; ++cch){
    int m0 = cch * CH;
    gemm_k<256,0,6><<<dim3(6, CH/128), 256, 0, stream>>>(xn, wqkv, qkvb, qkvc, nullptr, nullptr, m0, 0);
    attn_kernel<<<CH/49, 512, 0, stream>>>(qkvc, rpb, aoc, m0/49);
    gemm_k<256,1,2><<<dim3(2, CH/128), 256, 0, stream>>>(aoc, wproj, projb, x2, x, xl, 0, m0);
  }

  ln_kernel<<<25088, 256, 0, stream>>>(x2, ln2g, ln2b, xn);   // xn reused as LN2 out

  for (int cch = 0; cch < NC; ++cch){
    int m0 = cch * CH;
    gemm_k<256,2,8> <<<dim3(8, CH/128), 256, 0, stream>>>(xn,  wm1, b1, h1c, nullptr, nullptr, m0, 0);
    gemm_k<1024,2,8><<<dim3(8, CH/128), 256, 0, stream>>>(h1c, wm2, b2, h2c, nullptr, nullptr, 0, 0);
    gemm_k<1024,3,2><<<dim3(2, CH/128), 256, 0, stream>>>(h2c, wm3, b3, x2, x2, nullptr, 0, m0);
  }
}